// Round 2
// baseline (759.493 us; speedup 1.0000x reference)
//
#include <hip/hip_runtime.h>
#include <hip/hip_bf16.h>
#include <cstdint>
#include <cstddef>

#define D_MODEL   1024
#define NUM_HEADS 16
#define HEAD_DIM  64
#define SEQ       2048
#define BATCH     4
#define BH        (BATCH*NUM_HEADS)   // 64
#define MROWS     (BATCH*SEQ)         // 8192

typedef _Float16 half8  __attribute__((ext_vector_type(8)));
typedef _Float16 half4v __attribute__((ext_vector_type(4)));
typedef float    floatx4 __attribute__((ext_vector_type(4)));

// ---------------------------------------------------------------------------
// async global -> LDS, 16 bytes per lane. LDS base must be wave-uniform;
// HW writes lds_base + lane*16.
// ---------------------------------------------------------------------------
__device__ inline void gld_lds16(const void* g, void* l) {
    __builtin_amdgcn_global_load_lds(
        (__attribute__((address_space(1))) void*)g,
        (__attribute__((address_space(3))) void*)l,
        16, 0, 0);
}

// ---------------------------------------------------------------------------
// RoPE cos/sin table [s][p], p in [0,32): angle = s * 10000^(-p/32), fp64.
// ---------------------------------------------------------------------------
__global__ void rope_table(float2* __restrict__ tab) {
    const int i = blockIdx.x * blockDim.x + threadIdx.x;   // SEQ*32
    const int p = i & 31, s = i >> 5;
    const double inv = pow(10000.0, -(double)p / 32.0);
    const double ang = (double)s * inv;
    tab[i] = make_float2((float)cos(ang), (float)sin(ang));
}

// ---------------------------------------------------------------------------
// fp32 -> f16 (hi only), 4-wide
// ---------------------------------------------------------------------------
__global__ void f32_to_f16_v4(const float* __restrict__ in,
                              _Float16* __restrict__ out, int n4) {
    int i = blockIdx.x * blockDim.x + threadIdx.x;
    if (i >= n4) return;
    float4 v = ((const float4*)in)[i];
    half4v o = { (_Float16)v.x, (_Float16)v.y, (_Float16)v.z, (_Float16)v.w };
    ((half4v*)out)[i] = o;
}

// ---------------------------------------------------------------------------
// fp32 -> split f16 (hi + lo residual), 4-wide. v ~= hi + lo to ~2^-22.
// ---------------------------------------------------------------------------
__global__ void f32_split_f16(const float* __restrict__ in,
                              _Float16* __restrict__ hi,
                              _Float16* __restrict__ lo, int n4) {
    int i = blockIdx.x * blockDim.x + threadIdx.x;
    if (i >= n4) return;
    float4 v = ((const float4*)in)[i];
    half4v h = { (_Float16)v.x, (_Float16)v.y, (_Float16)v.z, (_Float16)v.w };
    half4v l = { (_Float16)(v.x - (float)h.x), (_Float16)(v.y - (float)h.y),
                 (_Float16)(v.z - (float)h.z), (_Float16)(v.w - (float)h.w) };
    ((half4v*)hi)[i] = h;
    ((half4v*)lo)[i] = l;
}

// ---------------------------------------------------------------------------
// Plain GEMM: C[m,n] = sum_k A[m,k] * B[n,k]. 128x128 tile, BK=32, 4 waves,
// mfma_f32_16x16x32_f16, global_load_lds width=16 (m97 structure).
// MODE 0: fp32 row-major MxN (final output)
// MODE 2: f16 head-split-T [b][h][d][s]  (V^T)
// ---------------------------------------------------------------------------
template<int MODE>
__global__ __launch_bounds__(256)
void gemm_bt(const _Float16* __restrict__ A, const _Float16* __restrict__ B,
             void* __restrict__ Cout, int M, int N, int K) {
    __shared__ _Float16 As[128*32];
    __shared__ _Float16 Bs[128*32];

    const int nb = N >> 7;
    const int bx = blockIdx.x % nb;
    const int by = blockIdx.x / nb;
    const int m0 = by << 7, n0 = bx << 7;

    const int t    = threadIdx.x;
    const int w    = t >> 6;
    const int lane = t & 63;
    const int r    = lane & 15;
    const int quad = lane >> 4;
    const int wm   = (w >> 1) << 6;
    const int wn   = (w & 1) << 6;

    const int srow = lane >> 2;
    const int scol = (lane & 3) << 3;

    floatx4 acc[4][4];
    #pragma unroll
    for (int i = 0; i < 4; i++)
        #pragma unroll
        for (int j = 0; j < 4; j++)
            acc[i][j] = (floatx4){0.f, 0.f, 0.f, 0.f};

    for (int k0 = 0; k0 < K; k0 += 32) {
        __syncthreads();
        #pragma unroll
        for (int p = 0; p < 2; ++p) {
            const int rbase = p*64 + w*16;
            gld_lds16(&A[(size_t)(m0 + rbase + srow)*K + k0 + scol], &As[rbase*32]);
            gld_lds16(&B[(size_t)(n0 + rbase + srow)*K + k0 + scol], &Bs[rbase*32]);
        }
        __syncthreads();

        half8 af[4], bf[4];
        #pragma unroll
        for (int i = 0; i < 4; i++)
            af[i] = *(const half8*)&As[(wm + i*16 + r)*32 + quad*8];
        #pragma unroll
        for (int j = 0; j < 4; j++)
            bf[j] = *(const half8*)&Bs[(wn + j*16 + r)*32 + quad*8];

        #pragma unroll
        for (int i = 0; i < 4; i++)
            #pragma unroll
            for (int j = 0; j < 4; j++)
                acc[i][j] = __builtin_amdgcn_mfma_f32_16x16x32_f16(
                                af[i], bf[j], acc[i][j], 0, 0, 0);
    }

    // C/D layout: col = lane&15, row = quad*4 + reg
    #pragma unroll
    for (int i = 0; i < 4; i++) {
        #pragma unroll
        for (int j = 0; j < 4; j++) {
            #pragma unroll
            for (int v = 0; v < 4; v++) {
                const int m = m0 + wm + i*16 + quad*4 + v;
                const int n = n0 + wn + j*16 + r;
                const float val = acc[i][j][v];
                if (MODE == 0) {
                    ((float*)Cout)[(size_t)m*N + n] = val;
                } else {
                    const int b = m >> 11, s = m & 2047;
                    const int h = n >> 6,  d = n & 63;
                    ((_Float16*)Cout)[((((size_t)b*NUM_HEADS + h)*HEAD_DIM + d) << 11) + s]
                        = (_Float16)val;
                }
            }
        }
    }
}

// ---------------------------------------------------------------------------
// Split-precision GEMM for Q/K projections with fused RoPE epilogue.
// C = (Ah+Al) @ (Bh+Bl)^T  ~=  Ah·Bh + Ah·Bl + Al·Bh   (3 MFMA chains)
// Epilogue: RoPE rotation via lane-pair shuffle + fp64-built cos/sin table,
// output split to f16 hi/lo planes, head-split layout [b][h][s][64].
// ---------------------------------------------------------------------------
__global__ __launch_bounds__(256)
void gemm_qk(const _Float16* __restrict__ Ah, const _Float16* __restrict__ Al,
             const _Float16* __restrict__ Bh, const _Float16* __restrict__ Bl,
             _Float16* __restrict__ Chi, _Float16* __restrict__ Clo,
             const float2* __restrict__ tab, int M, int N, int K) {
    __shared__ _Float16 Ash[128*32];
    __shared__ _Float16 Asl[128*32];
    __shared__ _Float16 Bsh[128*32];
    __shared__ _Float16 Bsl[128*32];

    const int nb = N >> 7;
    const int bx = blockIdx.x % nb;
    const int by = blockIdx.x / nb;
    const int m0 = by << 7, n0 = bx << 7;

    const int t    = threadIdx.x;
    const int w    = t >> 6;
    const int lane = t & 63;
    const int r    = lane & 15;
    const int quad = lane >> 4;
    const int wm   = (w >> 1) << 6;
    const int wn   = (w & 1) << 6;

    const int srow = lane >> 2;
    const int scol = (lane & 3) << 3;

    floatx4 acc[4][4];
    #pragma unroll
    for (int i = 0; i < 4; i++)
        #pragma unroll
        for (int j = 0; j < 4; j++)
            acc[i][j] = (floatx4){0.f, 0.f, 0.f, 0.f};

    for (int k0 = 0; k0 < K; k0 += 32) {
        __syncthreads();
        #pragma unroll
        for (int p = 0; p < 2; ++p) {
            const int rbase = p*64 + w*16;
            const size_t ga = (size_t)(m0 + rbase + srow)*K + k0 + scol;
            const size_t gb = (size_t)(n0 + rbase + srow)*K + k0 + scol;
            gld_lds16(&Ah[ga], &Ash[rbase*32]);
            gld_lds16(&Al[ga], &Asl[rbase*32]);
            gld_lds16(&Bh[gb], &Bsh[rbase*32]);
            gld_lds16(&Bl[gb], &Bsl[rbase*32]);
        }
        __syncthreads();

        half8 ah[4], al[4], bh[4], bl[4];
        #pragma unroll
        for (int i = 0; i < 4; i++) {
            ah[i] = *(const half8*)&Ash[(wm + i*16 + r)*32 + quad*8];
            al[i] = *(const half8*)&Asl[(wm + i*16 + r)*32 + quad*8];
        }
        #pragma unroll
        for (int j = 0; j < 4; j++) {
            bh[j] = *(const half8*)&Bsh[(wn + j*16 + r)*32 + quad*8];
            bl[j] = *(const half8*)&Bsl[(wn + j*16 + r)*32 + quad*8];
        }

        #pragma unroll
        for (int i = 0; i < 4; i++)
            #pragma unroll
            for (int j = 0; j < 4; j++) {
                acc[i][j] = __builtin_amdgcn_mfma_f32_16x16x32_f16(
                                ah[i], bh[j], acc[i][j], 0, 0, 0);
                acc[i][j] = __builtin_amdgcn_mfma_f32_16x16x32_f16(
                                ah[i], bl[j], acc[i][j], 0, 0, 0);
                acc[i][j] = __builtin_amdgcn_mfma_f32_16x16x32_f16(
                                al[i], bh[j], acc[i][j], 0, 0, 0);
            }
    }

    // Epilogue: RoPE + split-f16 store. Pair partner is lane^1 (adjacent n).
    #pragma unroll
    for (int i = 0; i < 4; i++) {
        #pragma unroll
        for (int v = 0; v < 4; v++) {
            const int m  = m0 + wm + i*16 + quad*4 + v;
            const int b  = m >> 11;
            const int s_ = m & 2047;
            #pragma unroll
            for (int j = 0; j < 4; j++) {
                const int n = n0 + wn + j*16 + r;
                const int h = n >> 6, d = n & 63;
                const float val = acc[i][j][v];
                const float pv  = __shfl_xor(val, 1);
                const float2 cs = tab[s_*32 + (d >> 1)];
                const float res = (r & 1) ? (pv*cs.y + val*cs.x)
                                          : (val*cs.x - pv*cs.y);
                const size_t idx = ((((size_t)b*NUM_HEADS + h)*SEQ + s_) << 6) + d;
                const _Float16 hv = (_Float16)res;
                Chi[idx] = hv;
                Clo[idx] = (_Float16)(res - (float)hv);
            }
        }
    }
}

// ---------------------------------------------------------------------------
// Causal flash attention, split-precision scores.
// 1 wave per (bh, 16 Q-rows), 32-key tiles.
// Qhi/Qlo, Khi/Klo: [bh][s][64] f16.  Vt: [bh][64][s] f16.
// AO: [b][s][h*64+d] f16.
// ---------------------------------------------------------------------------
__global__ __launch_bounds__(64)
void flash_attn(const _Float16* __restrict__ Qhi, const _Float16* __restrict__ Qlo,
                const _Float16* __restrict__ Khi, const _Float16* __restrict__ Klo,
                const _Float16* __restrict__ Vt,  _Float16* __restrict__ AO) {
    __shared__ _Float16 Plds[16*32];

    const int lane = threadIdx.x;
    const int r    = lane & 15;
    const int quad = lane >> 4;
    const int bh = blockIdx.x >> 7;
    const int qt = blockIdx.x & 127;
    const int q0 = qt << 4;
    const int b  = bh >> 4, h = bh & 15;

    const _Float16* Qh_ = Qhi + (size_t)bh * SEQ * HEAD_DIM;
    const _Float16* Ql_ = Qlo + (size_t)bh * SEQ * HEAD_DIM;
    const _Float16* Kh_ = Khi + (size_t)bh * SEQ * HEAD_DIM;
    const _Float16* Kl_ = Klo + (size_t)bh * SEQ * HEAD_DIM;
    const _Float16* Vh  = Vt  + (size_t)bh * HEAD_DIM * SEQ;

    // Q A-fragments (hi and lo), d split [0,32) / [32,64)
    const half8 qh0 = *(const half8*)&Qh_[(size_t)(q0 + r)*64 + quad*8];
    const half8 qh1 = *(const half8*)&Qh_[(size_t)(q0 + r)*64 + 32 + quad*8];
    const half8 ql0 = *(const half8*)&Ql_[(size_t)(q0 + r)*64 + quad*8];
    const half8 ql1 = *(const half8*)&Ql_[(size_t)(q0 + r)*64 + 32 + quad*8];

    floatx4 o0 = {0.f,0.f,0.f,0.f}, o1 = {0.f,0.f,0.f,0.f};
    floatx4 o2 = {0.f,0.f,0.f,0.f}, o3 = {0.f,0.f,0.f,0.f};
    float mi[4] = {-1e30f, -1e30f, -1e30f, -1e30f};
    float li[4] = {0.f, 0.f, 0.f, 0.f};

    const int ntiles = (q0 + 16 + 31) >> 5;
    for (int kt = 0; kt < ntiles; ++kt) {
        const int k0 = kt << 5;

        floatx4 sc[2] = {{0.f,0.f,0.f,0.f}, {0.f,0.f,0.f,0.f}};
        #pragma unroll
        for (int n = 0; n < 2; n++) {
            const size_t kb = (size_t)(k0 + n*16 + r)*64;
            const half8 kh0 = *(const half8*)&Kh_[kb + quad*8];
            const half8 kh1 = *(const half8*)&Kh_[kb + 32 + quad*8];
            const half8 kl0 = *(const half8*)&Kl_[kb + quad*8];
            const half8 kl1 = *(const half8*)&Kl_[kb + 32 + quad*8];
            sc[n] = __builtin_amdgcn_mfma_f32_16x16x32_f16(qh0, kh0, sc[n], 0, 0, 0);
            sc[n] = __builtin_amdgcn_mfma_f32_16x16x32_f16(qh1, kh1, sc[n], 0, 0, 0);
            sc[n] = __builtin_amdgcn_mfma_f32_16x16x32_f16(qh0, kl0, sc[n], 0, 0, 0);
            sc[n] = __builtin_amdgcn_mfma_f32_16x16x32_f16(qh1, kl1, sc[n], 0, 0, 0);
            sc[n] = __builtin_amdgcn_mfma_f32_16x16x32_f16(ql0, kh0, sc[n], 0, 0, 0);
            sc[n] = __builtin_amdgcn_mfma_f32_16x16x32_f16(ql1, kh1, sc[n], 0, 0, 0);
        }

        // scale + causal mask; row = q0 + quad*4 + v, col = k0 + n*16 + r
        float p[2][4], tmax[4];
        #pragma unroll
        for (int v = 0; v < 4; v++) {
            const int row = q0 + quad*4 + v;
            float s0 = sc[0][v] * 0.125f;  if (k0 + r      > row) s0 = -1e30f;
            float s1 = sc[1][v] * 0.125f;  if (k0 + 16 + r > row) s1 = -1e30f;
            p[0][v] = s0; p[1][v] = s1;
            tmax[v] = fmaxf(s0, s1);
        }
        #pragma unroll
        for (int v = 0; v < 4; v++) {
            float tv = tmax[v];
            tv = fmaxf(tv, __shfl_xor(tv, 1));
            tv = fmaxf(tv, __shfl_xor(tv, 2));
            tv = fmaxf(tv, __shfl_xor(tv, 4));
            tv = fmaxf(tv, __shfl_xor(tv, 8));
            tmax[v] = tv;
        }
        float alpha[4];
        #pragma unroll
        for (int v = 0; v < 4; v++) {
            const float nm = fmaxf(mi[v], tmax[v]);
            alpha[v] = __expf(mi[v] - nm);
            mi[v] = nm;
            const float p0 = __expf(p[0][v] - nm);
            const float p1 = __expf(p[1][v] - nm);
            p[0][v] = p0; p[1][v] = p1;
            float rs = p0 + p1;
            rs += __shfl_xor(rs, 1);
            rs += __shfl_xor(rs, 2);
            rs += __shfl_xor(rs, 4);
            rs += __shfl_xor(rs, 8);
            li[v] = li[v]*alpha[v] + rs;
        }
        #pragma unroll
        for (int v = 0; v < 4; v++) {
            o0[v] *= alpha[v]; o1[v] *= alpha[v];
            o2[v] *= alpha[v]; o3[v] *= alpha[v];
        }

        // P: C-layout -> LDS -> A-layout
        __syncthreads();
        #pragma unroll
        for (int v = 0; v < 4; v++) {
            Plds[(quad*4 + v)*32 + r]      = (_Float16)p[0][v];
            Plds[(quad*4 + v)*32 + 16 + r] = (_Float16)p[1][v];
        }
        __syncthreads();
        const half8 pf = *(const half8*)&Plds[r*32 + quad*8];

        const half8 v0 = *(const half8*)&Vh[(size_t)( 0 + r)*SEQ + k0 + quad*8];
        const half8 v1 = *(const half8*)&Vh[(size_t)(16 + r)*SEQ + k0 + quad*8];
        const half8 v2 = *(const half8*)&Vh[(size_t)(32 + r)*SEQ + k0 + quad*8];
        const half8 v3 = *(const half8*)&Vh[(size_t)(48 + r)*SEQ + k0 + quad*8];
        o0 = __builtin_amdgcn_mfma_f32_16x16x32_f16(pf, v0, o0, 0, 0, 0);
        o1 = __builtin_amdgcn_mfma_f32_16x16x32_f16(pf, v1, o1, 0, 0, 0);
        o2 = __builtin_amdgcn_mfma_f32_16x16x32_f16(pf, v2, o2, 0, 0, 0);
        o3 = __builtin_amdgcn_mfma_f32_16x16x32_f16(pf, v3, o3, 0, 0, 0);
    }

    #pragma unroll
    for (int v = 0; v < 4; v++) {
        const int s_ = q0 + quad*4 + v;
        const float inv = 1.0f / li[v];
        const size_t base = ((size_t)(b*SEQ + s_))*D_MODEL + h*HEAD_DIM + r;
        AO[base]      = (_Float16)(o0[v]*inv);
        AO[base + 16] = (_Float16)(o1[v]*inv);
        AO[base + 32] = (_Float16)(o2[v]*inv);
        AO[base + 48] = (_Float16)(o3[v]*inv);
    }
}

// ---------------------------------------------------------------------------
extern "C" void kernel_launch(void* const* d_in, const int* in_sizes, int n_in,
                              void* d_out, int out_size, void* d_ws, size_t ws_size,
                              hipStream_t stream) {
    const float* x  = (const float*)d_in[0];
    const float* qw = (const float*)d_in[1];
    const float* kw = (const float*)d_in[2];
    const float* vw = (const float*)d_in[3];
    const float* ow = (const float*)d_in[4];
    float* out = (float*)d_out;

    // workspace layout (_Float16 counts), total ~147.3 MB
    _Float16* xh  = (_Float16*)d_ws;
    _Float16* xl  = xh  + (size_t)MROWS * D_MODEL;
    _Float16* qwh = xl  + (size_t)MROWS * D_MODEL;
    _Float16* qwl = qwh + (size_t)D_MODEL * D_MODEL;
    _Float16* kwh = qwl + (size_t)D_MODEL * D_MODEL;
    _Float16* kwl = kwh + (size_t)D_MODEL * D_MODEL;
    _Float16* vwh = kwl + (size_t)D_MODEL * D_MODEL;
    _Float16* owh = vwh + (size_t)D_MODEL * D_MODEL;
    _Float16* Qhi = owh + (size_t)D_MODEL * D_MODEL;
    _Float16* Qlo = Qhi + (size_t)MROWS * D_MODEL;
    _Float16* Khi = Qlo + (size_t)MROWS * D_MODEL;
    _Float16* Klo = Khi + (size_t)MROWS * D_MODEL;
    _Float16* Vt  = Klo + (size_t)MROWS * D_MODEL;
    _Float16* AO  = Vt  + (size_t)MROWS * D_MODEL;
    float2*   tab = (float2*)(AO + (size_t)MROWS * D_MODEL);

    rope_table<<<(SEQ*32)/256, 256, 0, stream>>>(tab);

    const int nx4 = MROWS * D_MODEL / 4;
    f32_split_f16<<<nx4/256, 256, 0, stream>>>(x, xh, xl, nx4);
    const int nw4 = D_MODEL * D_MODEL / 4;
    f32_split_f16<<<nw4/256, 256, 0, stream>>>(qw, qwh, qwl, nw4);
    f32_split_f16<<<nw4/256, 256, 0, stream>>>(kw, kwh, kwl, nw4);
    f32_to_f16_v4<<<nw4/256, 256, 0, stream>>>(vw, vwh, nw4);
    f32_to_f16_v4<<<nw4/256, 256, 0, stream>>>(ow, owh, nw4);

    const int gemm_grid = (MROWS/128) * (D_MODEL/128);   // 512
    gemm_qk<<<gemm_grid, 256, 0, stream>>>(xh, xl, qwh, qwl, Qhi, Qlo, tab,
                                           MROWS, D_MODEL, D_MODEL);
    gemm_qk<<<gemm_grid, 256, 0, stream>>>(xh, xl, kwh, kwl, Khi, Klo, tab,
                                           MROWS, D_MODEL, D_MODEL);
    gemm_bt<2><<<gemm_grid, 256, 0, stream>>>(xh, vwh, Vt, MROWS, D_MODEL, D_MODEL);

    flash_attn<<<BH * (SEQ/16), 64, 0, stream>>>(Qhi, Qlo, Khi, Klo, Vt, AO);

    gemm_bt<0><<<gemm_grid, 256, 0, stream>>>(AO, owh, out, MROWS, D_MODEL, D_MODEL);
}

// Round 3
// 458.112 us; speedup vs baseline: 1.6579x; 1.6579x over previous
//
#include <hip/hip_runtime.h>
#include <hip/hip_bf16.h>
#include <cstdint>
#include <cstddef>

#define D_MODEL   1024
#define NUM_HEADS 16
#define HEAD_DIM  64
#define SEQ       2048
#define BATCH     4
#define BH        (BATCH*NUM_HEADS)   // 64
#define MROWS     (BATCH*SEQ)         // 8192

typedef _Float16 half8  __attribute__((ext_vector_type(8)));
typedef _Float16 half4v __attribute__((ext_vector_type(4)));
typedef float    floatx4 __attribute__((ext_vector_type(4)));

// ---------------------------------------------------------------------------
// async global -> LDS, 16 bytes per lane. LDS base must be wave-uniform;
// HW writes lds_base + lane*16.
// ---------------------------------------------------------------------------
__device__ inline void gld_lds16(const void* g, void* l) {
    __builtin_amdgcn_global_load_lds(
        (__attribute__((address_space(1))) void*)g,
        (__attribute__((address_space(3))) void*)l,
        16, 0, 0);
}

// ---------------------------------------------------------------------------
// RoPE cos/sin table [s][p], p in [0,32): angle = s * 10000^(-p/32), fp64.
// ---------------------------------------------------------------------------
__global__ void rope_table(float2* __restrict__ tab) {
    const int i = blockIdx.x * blockDim.x + threadIdx.x;   // SEQ*32
    const int p = i & 31, s = i >> 5;
    const double inv = pow(10000.0, -(double)p / 32.0);
    const double ang = (double)s * inv;
    tab[i] = make_float2((float)cos(ang), (float)sin(ang));
}

// ---------------------------------------------------------------------------
// fp32 -> f16 (hi only), 4-wide
// ---------------------------------------------------------------------------
__global__ void f32_to_f16_v4(const float* __restrict__ in,
                              _Float16* __restrict__ out, int n4) {
    int i = blockIdx.x * blockDim.x + threadIdx.x;
    if (i >= n4) return;
    float4 v = ((const float4*)in)[i];
    half4v o = { (_Float16)v.x, (_Float16)v.y, (_Float16)v.z, (_Float16)v.w };
    ((half4v*)out)[i] = o;
}

// ---------------------------------------------------------------------------
// fp32 -> split f16 (hi + lo residual), 4-wide. v ~= hi + lo to ~2^-22.
// ---------------------------------------------------------------------------
__global__ void f32_split_f16(const float* __restrict__ in,
                              _Float16* __restrict__ hi,
                              _Float16* __restrict__ lo, int n4) {
    int i = blockIdx.x * blockDim.x + threadIdx.x;
    if (i >= n4) return;
    float4 v = ((const float4*)in)[i];
    half4v h = { (_Float16)v.x, (_Float16)v.y, (_Float16)v.z, (_Float16)v.w };
    half4v l = { (_Float16)(v.x - (float)h.x), (_Float16)(v.y - (float)h.y),
                 (_Float16)(v.z - (float)h.z), (_Float16)(v.w - (float)h.w) };
    ((half4v*)hi)[i] = h;
    ((half4v*)lo)[i] = l;
}

// ---------------------------------------------------------------------------
// Plain GEMM: C[m,n] = sum_k A[m,k] * B[n,k]. 128x128 tile, BK=32, 4 waves,
// mfma_f32_16x16x32_f16, global_load_lds width=16 (m97 structure).
// MODE 0: fp32 row-major MxN (final output)
// MODE 2: f16 head-split-T [b][h][d][s]  (V^T)
// ---------------------------------------------------------------------------
template<int MODE>
__global__ __launch_bounds__(256)
void gemm_bt(const _Float16* __restrict__ A, const _Float16* __restrict__ B,
             void* __restrict__ Cout, int M, int N, int K) {
    __shared__ _Float16 As[128*32];
    __shared__ _Float16 Bs[128*32];

    const int nb = N >> 7;
    const int bx = blockIdx.x % nb;
    const int by = blockIdx.x / nb;
    const int m0 = by << 7, n0 = bx << 7;

    const int t    = threadIdx.x;
    const int w    = t >> 6;
    const int lane = t & 63;
    const int r    = lane & 15;
    const int quad = lane >> 4;
    const int wm   = (w >> 1) << 6;
    const int wn   = (w & 1) << 6;

    const int srow = lane >> 2;
    const int scol = (lane & 3) << 3;

    floatx4 acc[4][4];
    #pragma unroll
    for (int i = 0; i < 4; i++)
        #pragma unroll
        for (int j = 0; j < 4; j++)
            acc[i][j] = (floatx4){0.f, 0.f, 0.f, 0.f};

    for (int k0 = 0; k0 < K; k0 += 32) {
        __syncthreads();
        #pragma unroll
        for (int p = 0; p < 2; ++p) {
            const int rbase = p*64 + w*16;
            gld_lds16(&A[(size_t)(m0 + rbase + srow)*K + k0 + scol], &As[rbase*32]);
            gld_lds16(&B[(size_t)(n0 + rbase + srow)*K + k0 + scol], &Bs[rbase*32]);
        }
        __syncthreads();

        half8 af[4], bf[4];
        #pragma unroll
        for (int i = 0; i < 4; i++)
            af[i] = *(const half8*)&As[(wm + i*16 + r)*32 + quad*8];
        #pragma unroll
        for (int j = 0; j < 4; j++)
            bf[j] = *(const half8*)&Bs[(wn + j*16 + r)*32 + quad*8];

        #pragma unroll
        for (int i = 0; i < 4; i++)
            #pragma unroll
            for (int j = 0; j < 4; j++)
                acc[i][j] = __builtin_amdgcn_mfma_f32_16x16x32_f16(
                                af[i], bf[j], acc[i][j], 0, 0, 0);
    }

    // C/D layout: col = lane&15, row = quad*4 + reg
    #pragma unroll
    for (int i = 0; i < 4; i++) {
        #pragma unroll
        for (int j = 0; j < 4; j++) {
            #pragma unroll
            for (int v = 0; v < 4; v++) {
                const int m = m0 + wm + i*16 + quad*4 + v;
                const int n = n0 + wn + j*16 + r;
                const float val = acc[i][j][v];
                if (MODE == 0) {
                    ((float*)Cout)[(size_t)m*N + n] = val;
                } else {
                    const int b = m >> 11, s = m & 2047;
                    const int h = n >> 6,  d = n & 63;
                    ((_Float16*)Cout)[((((size_t)b*NUM_HEADS + h)*HEAD_DIM + d) << 11) + s]
                        = (_Float16)val;
                }
            }
        }
    }
}

// ---------------------------------------------------------------------------
// Split-precision GEMM for Q/K projections with fused RoPE epilogue.
// C = (Ah+Al) @ (Bh+Bl)^T  ~=  Ah·Bh + Ah·Bl + Al·Bh   (3 MFMA chains)
// ---------------------------------------------------------------------------
__global__ __launch_bounds__(256)
void gemm_qk(const _Float16* __restrict__ Ah, const _Float16* __restrict__ Al,
             const _Float16* __restrict__ Bh, const _Float16* __restrict__ Bl,
             _Float16* __restrict__ Chi, _Float16* __restrict__ Clo,
             const float2* __restrict__ tab, int M, int N, int K) {
    __shared__ _Float16 Ash[128*32];
    __shared__ _Float16 Asl[128*32];
    __shared__ _Float16 Bsh[128*32];
    __shared__ _Float16 Bsl[128*32];

    const int nb = N >> 7;
    const int bx = blockIdx.x % nb;
    const int by = blockIdx.x / nb;
    const int m0 = by << 7, n0 = bx << 7;

    const int t    = threadIdx.x;
    const int w    = t >> 6;
    const int lane = t & 63;
    const int r    = lane & 15;
    const int quad = lane >> 4;
    const int wm   = (w >> 1) << 6;
    const int wn   = (w & 1) << 6;

    const int srow = lane >> 2;
    const int scol = (lane & 3) << 3;

    floatx4 acc[4][4];
    #pragma unroll
    for (int i = 0; i < 4; i++)
        #pragma unroll
        for (int j = 0; j < 4; j++)
            acc[i][j] = (floatx4){0.f, 0.f, 0.f, 0.f};

    for (int k0 = 0; k0 < K; k0 += 32) {
        __syncthreads();
        #pragma unroll
        for (int p = 0; p < 2; ++p) {
            const int rbase = p*64 + w*16;
            const size_t ga = (size_t)(m0 + rbase + srow)*K + k0 + scol;
            const size_t gb = (size_t)(n0 + rbase + srow)*K + k0 + scol;
            gld_lds16(&Ah[ga], &Ash[rbase*32]);
            gld_lds16(&Al[ga], &Asl[rbase*32]);
            gld_lds16(&Bh[gb], &Bsh[rbase*32]);
            gld_lds16(&Bl[gb], &Bsl[rbase*32]);
        }
        __syncthreads();

        half8 ah[4], al[4], bh[4], bl[4];
        #pragma unroll
        for (int i = 0; i < 4; i++) {
            ah[i] = *(const half8*)&Ash[(wm + i*16 + r)*32 + quad*8];
            al[i] = *(const half8*)&Asl[(wm + i*16 + r)*32 + quad*8];
        }
        #pragma unroll
        for (int j = 0; j < 4; j++) {
            bh[j] = *(const half8*)&Bsh[(wn + j*16 + r)*32 + quad*8];
            bl[j] = *(const half8*)&Bsl[(wn + j*16 + r)*32 + quad*8];
        }

        #pragma unroll
        for (int i = 0; i < 4; i++)
            #pragma unroll
            for (int j = 0; j < 4; j++) {
                acc[i][j] = __builtin_amdgcn_mfma_f32_16x16x32_f16(
                                ah[i], bh[j], acc[i][j], 0, 0, 0);
                acc[i][j] = __builtin_amdgcn_mfma_f32_16x16x32_f16(
                                ah[i], bl[j], acc[i][j], 0, 0, 0);
                acc[i][j] = __builtin_amdgcn_mfma_f32_16x16x32_f16(
                                al[i], bh[j], acc[i][j], 0, 0, 0);
            }
    }

    // Epilogue: RoPE + split-f16 store. Pair partner is lane^1 (adjacent n).
    #pragma unroll
    for (int i = 0; i < 4; i++) {
        #pragma unroll
        for (int v = 0; v < 4; v++) {
            const int m  = m0 + wm + i*16 + quad*4 + v;
            const int b  = m >> 11;
            const int s_ = m & 2047;
            #pragma unroll
            for (int j = 0; j < 4; j++) {
                const int n = n0 + wn + j*16 + r;
                const int h = n >> 6, d = n & 63;
                const float val = acc[i][j][v];
                const float pv  = __shfl_xor(val, 1);
                const float2 cs = tab[s_*32 + (d >> 1)];
                const float res = (r & 1) ? (pv*cs.y + val*cs.x)
                                          : (val*cs.x - pv*cs.y);
                const size_t idx = ((((size_t)b*NUM_HEADS + h)*SEQ + s_) << 6) + d;
                const _Float16 hv = (_Float16)res;
                Chi[idx] = hv;
                Clo[idx] = (_Float16)(res - (float)hv);
            }
        }
    }
}

// ---------------------------------------------------------------------------
// Causal flash attention, block-cooperative, transposed scores.
// 256 threads = 4 waves; block handles 64 Q-rows (wave w: rows q0+w*16..+15).
// 64-key iterations; Khi/Klo/V^T tiles staged in LDS via global_load_lds.
// S^T = K·Q^T  (q lives in lane&15 -> softmax reductions are 2 shuffles).
// O^T = V^T·P  (q also in lane&15 -> alpha rescale is shuffle-free).
// Longest blocks launch first (LPT) to kill the drain tail.
// ---------------------------------------------------------------------------
#define PSTR 72   // P strip stride in f16 (16B-aligned rows, breaks worst banks)
__global__ __launch_bounds__(256)
void flash_attn(const _Float16* __restrict__ Qhi, const _Float16* __restrict__ Qlo,
                const _Float16* __restrict__ Khi, const _Float16* __restrict__ Klo,
                const _Float16* __restrict__ Vt,  _Float16* __restrict__ AO) {
    __shared__ _Float16 Ksh[64*64];
    __shared__ _Float16 Ksl[64*64];
    __shared__ _Float16 Vs [64*64];
    __shared__ _Float16 Pl [4][16*PSTR];

    const int t    = threadIdx.x;
    const int w    = t >> 6;
    const int lane = t & 63;
    const int r    = lane & 15;
    const int quad = lane >> 4;

    const int bx = blockIdx.x;
    const int bh = bx & 63;                 // 64 bh, fastest
    const int qb = 31 - (bx >> 6);          // 32 q-blocks, longest first
    const int q0w = qb*64 + w*16;
    const int b  = bh >> 4, h = bh & 15;

    const _Float16* Qh_ = Qhi + (size_t)bh * SEQ * HEAD_DIM;
    const _Float16* Ql_ = Qlo + (size_t)bh * SEQ * HEAD_DIM;
    const _Float16* Khg = Khi + (size_t)bh * SEQ * HEAD_DIM;
    const _Float16* Klg = Klo + (size_t)bh * SEQ * HEAD_DIM;
    const _Float16* Vtg = Vt  + (size_t)bh * HEAD_DIM * SEQ;

    // Q B-fragments: B[n=q=r][k=d=c*32+quad*8+j], hi and lo
    half8 qh[2], ql[2];
    #pragma unroll
    for (int c = 0; c < 2; ++c) {
        qh[c] = *(const half8*)&Qh_[(size_t)(q0w + r)*64 + c*32 + quad*8];
        ql[c] = *(const half8*)&Ql_[(size_t)(q0w + r)*64 + c*32 + quad*8];
    }

    // O^T accumulators: tile d = dt*16+quad*4+v, col q = r
    floatx4 ot[4];
    #pragma unroll
    for (int dt = 0; dt < 4; ++dt) ot[dt] = (floatx4){0.f,0.f,0.f,0.f};
    float mi = -1e30f, li = 0.f;

    const int sr8 = lane >> 3;            // staging: 8 lanes per 64-f16 row
    const int sc8 = (lane & 7) << 3;

    const int niter = qb + 1;
    for (int kt = 0; kt < niter; ++kt) {
        const int k0 = kt << 6;

        __syncthreads();                  // prior iter's LDS reads complete
        #pragma unroll
        for (int i = 0; i < 2; ++i) {
            const int rb  = w*16 + i*8;   // wave-uniform tile-row base
            const int row = rb + sr8;
            gld_lds16(&Khg[(size_t)(k0 + row)*64 + sc8], &Ksh[rb*64]);
            gld_lds16(&Klg[(size_t)(k0 + row)*64 + sc8], &Ksl[rb*64]);
            gld_lds16(&Vtg[(size_t)row*SEQ + k0 + sc8],  &Vs [rb*64]);
        }
        __syncthreads();                  // vmcnt(0): staging complete

        // S^T = K·Q^T : 16 scores per lane (key = sub*16+quad*4+v, q = r)
        float s[16];
        #pragma unroll
        for (int sub = 0; sub < 4; ++sub) {
            floatx4 a = (floatx4){0.f,0.f,0.f,0.f};
            #pragma unroll
            for (int c = 0; c < 2; ++c) {
                const half8 kh = *(const half8*)&Ksh[(sub*16 + r)*64 + c*32 + quad*8];
                const half8 kl = *(const half8*)&Ksl[(sub*16 + r)*64 + c*32 + quad*8];
                a = __builtin_amdgcn_mfma_f32_16x16x32_f16(kh, qh[c], a, 0, 0, 0);
                a = __builtin_amdgcn_mfma_f32_16x16x32_f16(kh, ql[c], a, 0, 0, 0);
                a = __builtin_amdgcn_mfma_f32_16x16x32_f16(kl, qh[c], a, 0, 0, 0);
            }
            #pragma unroll
            for (int v = 0; v < 4; ++v) s[sub*4 + v] = a[v] * 0.125f;
        }

        if (kt == niter - 1) {            // causal mask only in the last tile
            #pragma unroll
            for (int sub = 0; sub < 4; ++sub)
                #pragma unroll
                for (int v = 0; v < 4; ++v)
                    if (k0 + sub*16 + quad*4 + v > q0w + r)
                        s[sub*4 + v] = -1e30f;
        }

        // online softmax over this tile's 64 keys (per lane: q = r)
        float tm = s[0];
        #pragma unroll
        for (int i = 1; i < 16; ++i) tm = fmaxf(tm, s[i]);
        tm = fmaxf(tm, __shfl_xor(tm, 16));
        tm = fmaxf(tm, __shfl_xor(tm, 32));
        const float mn = fmaxf(mi, tm);
        const float alpha = __expf(mi - mn);
        mi = mn;
        float rs = 0.f;
        #pragma unroll
        for (int i = 0; i < 16; ++i) { s[i] = __expf(s[i] - mn); rs += s[i]; }
        rs += __shfl_xor(rs, 16);
        rs += __shfl_xor(rs, 32);
        li = li*alpha + rs;
        #pragma unroll
        for (int dt = 0; dt < 4; ++dt)
            #pragma unroll
            for (int v = 0; v < 4; ++v) ot[dt][v] *= alpha;

        // P^T -> per-wave LDS strip [q=r][key], packed 4-wide
        #pragma unroll
        for (int sub = 0; sub < 4; ++sub) {
            half4v pk = { (_Float16)s[sub*4+0], (_Float16)s[sub*4+1],
                          (_Float16)s[sub*4+2], (_Float16)s[sub*4+3] };
            *(half4v*)&Pl[w][r*PSTR + sub*16 + quad*4] = pk;
        }
        // (same-wave write->read: compiler inserts lgkmcnt wait, no barrier)

        // O^T += V^T·P : A = V^T-frag [m=d][k=key], B = P [n=q][k=key]
        #pragma unroll
        for (int c = 0; c < 2; ++c) {
            const half8 pf = *(const half8*)&Pl[w][r*PSTR + c*32 + quad*8];
            #pragma unroll
            for (int dt = 0; dt < 4; ++dt) {
                const half8 vf = *(const half8*)&Vs[(dt*16 + r)*64 + c*32 + quad*8];
                ot[dt] = __builtin_amdgcn_mfma_f32_16x16x32_f16(vf, pf, ot[dt], 0, 0, 0);
            }
        }
    }

    // epilogue: normalize, write AO [b][s=q][h*64 + d] (8B stores)
    const float inv = 1.0f / li;
    const int q = q0w + r;
    #pragma unroll
    for (int dt = 0; dt < 4; ++dt) {
        half4v o = { (_Float16)(ot[dt][0]*inv), (_Float16)(ot[dt][1]*inv),
                     (_Float16)(ot[dt][2]*inv), (_Float16)(ot[dt][3]*inv) };
        *(half4v*)&AO[((size_t)(b*SEQ + q))*D_MODEL + h*HEAD_DIM + dt*16 + quad*4] = o;
    }
}

// ---------------------------------------------------------------------------
extern "C" void kernel_launch(void* const* d_in, const int* in_sizes, int n_in,
                              void* d_out, int out_size, void* d_ws, size_t ws_size,
                              hipStream_t stream) {
    const float* x  = (const float*)d_in[0];
    const float* qw = (const float*)d_in[1];
    const float* kw = (const float*)d_in[2];
    const float* vw = (const float*)d_in[3];
    const float* ow = (const float*)d_in[4];
    float* out = (float*)d_out;

    // workspace layout (_Float16 counts), total ~147.3 MB
    _Float16* xh  = (_Float16*)d_ws;
    _Float16* xl  = xh  + (size_t)MROWS * D_MODEL;
    _Float16* qwh = xl  + (size_t)MROWS * D_MODEL;
    _Float16* qwl = qwh + (size_t)D_MODEL * D_MODEL;
    _Float16* kwh = qwl + (size_t)D_MODEL * D_MODEL;
    _Float16* kwl = kwh + (size_t)D_MODEL * D_MODEL;
    _Float16* vwh = kwl + (size_t)D_MODEL * D_MODEL;
    _Float16* owh = vwh + (size_t)D_MODEL * D_MODEL;
    _Float16* Qhi = owh + (size_t)D_MODEL * D_MODEL;
    _Float16* Qlo = Qhi + (size_t)MROWS * D_MODEL;
    _Float16* Khi = Qlo + (size_t)MROWS * D_MODEL;
    _Float16* Klo = Khi + (size_t)MROWS * D_MODEL;
    _Float16* Vt  = Klo + (size_t)MROWS * D_MODEL;
    _Float16* AO  = Vt  + (size_t)MROWS * D_MODEL;
    float2*   tab = (float2*)(AO + (size_t)MROWS * D_MODEL);

    rope_table<<<(SEQ*32)/256, 256, 0, stream>>>(tab);

    const int nx4 = MROWS * D_MODEL / 4;
    f32_split_f16<<<nx4/256, 256, 0, stream>>>(x, xh, xl, nx4);
    const int nw4 = D_MODEL * D_MODEL / 4;
    f32_split_f16<<<nw4/256, 256, 0, stream>>>(qw, qwh, qwl, nw4);
    f32_split_f16<<<nw4/256, 256, 0, stream>>>(kw, kwh, kwl, nw4);
    f32_to_f16_v4<<<nw4/256, 256, 0, stream>>>(vw, vwh, nw4);
    f32_to_f16_v4<<<nw4/256, 256, 0, stream>>>(ow, owh, nw4);

    const int gemm_grid = (MROWS/128) * (D_MODEL/128);   // 512
    gemm_qk<<<gemm_grid, 256, 0, stream>>>(xh, xl, qwh, qwl, Qhi, Qlo, tab,
                                           MROWS, D_MODEL, D_MODEL);
    gemm_qk<<<gemm_grid, 256, 0, stream>>>(xh, xl, kwh, kwl, Khi, Klo, tab,
                                           MROWS, D_MODEL, D_MODEL);
    gemm_bt<2><<<gemm_grid, 256, 0, stream>>>(xh, vwh, Vt, MROWS, D_MODEL, D_MODEL);

    flash_attn<<<BH * (SEQ/64), 256, 0, stream>>>(Qhi, Qlo, Khi, Klo, Vt, AO);

    gemm_bt<0><<<gemm_grid, 256, 0, stream>>>(AO, owh, out, MROWS, D_MODEL, D_MODEL);
}

// Round 5
// 393.428 us; speedup vs baseline: 1.9305x; 1.1644x over previous
//
#include <hip/hip_runtime.h>
#include <hip/hip_bf16.h>
#include <cstdint>
#include <cstddef>

#define D_MODEL   1024
#define NUM_HEADS 16
#define HEAD_DIM  64
#define SEQ       2048
#define BATCH     4
#define BH        (BATCH*NUM_HEADS)   // 64
#define MROWS     (BATCH*SEQ)         // 8192

typedef _Float16 half8  __attribute__((ext_vector_type(8)));
typedef _Float16 half4v __attribute__((ext_vector_type(4)));
typedef float    floatx4 __attribute__((ext_vector_type(4)));

// ---------------------------------------------------------------------------
// async global -> LDS, 16 bytes per lane. LDS base must be wave-uniform;
// HW writes lds_base + lane*16 (LDS side contiguous; global side per-lane).
// ---------------------------------------------------------------------------
__device__ inline void gld_lds16(const void* g, void* l) {
    __builtin_amdgcn_global_load_lds(
        (__attribute__((address_space(1))) void*)g,
        (__attribute__((address_space(3))) void*)l,
        16, 0, 0);
}

// ---------------------------------------------------------------------------
// RoPE cos/sin table [s][p], p in [0,32): angle = s * 10000^(-p/32), fp64.
// ---------------------------------------------------------------------------
__global__ void rope_table(float2* __restrict__ tab) {
    const int i = blockIdx.x * blockDim.x + threadIdx.x;   // SEQ*32
    const int p = i & 31, s = i >> 5;
    const double inv = pow(10000.0, -(double)p / 32.0);
    const double ang = (double)s * inv;
    tab[i] = make_float2((float)cos(ang), (float)sin(ang));
}

// ---------------------------------------------------------------------------
// fp32 -> f16 (hi only), 4-wide
// ---------------------------------------------------------------------------
__global__ void f32_to_f16_v4(const float* __restrict__ in,
                              _Float16* __restrict__ out, int n4) {
    int i = blockIdx.x * blockDim.x + threadIdx.x;
    if (i >= n4) return;
    float4 v = ((const float4*)in)[i];
    half4v o = { (_Float16)v.x, (_Float16)v.y, (_Float16)v.z, (_Float16)v.w };
    ((half4v*)out)[i] = o;
}

// ---------------------------------------------------------------------------
// fp32 -> split f16 (hi + lo residual), 4-wide. v ~= hi + lo to ~2^-22.
// ---------------------------------------------------------------------------
__global__ void f32_split_f16(const float* __restrict__ in,
                              _Float16* __restrict__ hi,
                              _Float16* __restrict__ lo, int n4) {
    int i = blockIdx.x * blockDim.x + threadIdx.x;
    if (i >= n4) return;
    float4 v = ((const float4*)in)[i];
    half4v h = { (_Float16)v.x, (_Float16)v.y, (_Float16)v.z, (_Float16)v.w };
    half4v l = { (_Float16)(v.x - (float)h.x), (_Float16)(v.y - (float)h.y),
                 (_Float16)(v.z - (float)h.z), (_Float16)(v.w - (float)h.w) };
    ((half4v*)hi)[i] = h;
    ((half4v*)lo)[i] = l;
}

// ---------------------------------------------------------------------------
// Plain GEMM: C[m,n] = sum_k A[m,k] * B[n,k]. 128x128 tile, BK=32, 4 waves,
// mfma_f32_16x16x32_f16, global_load_lds width=16 (m97 structure).
// MODE 0: fp32 row-major MxN (final output)
// MODE 2: f16 head-split-T [b][h][d][s]  (V^T)   — plain, no swizzle
// ---------------------------------------------------------------------------
template<int MODE>
__global__ __launch_bounds__(256)
void gemm_bt(const _Float16* __restrict__ A, const _Float16* __restrict__ B,
             void* __restrict__ Cout, int M, int N, int K) {
    __shared__ _Float16 As[128*32];
    __shared__ _Float16 Bs[128*32];

    const int nb = N >> 7;
    const int bx = blockIdx.x % nb;
    const int by = blockIdx.x / nb;
    const int m0 = by << 7, n0 = bx << 7;

    const int t    = threadIdx.x;
    const int w    = t >> 6;
    const int lane = t & 63;
    const int r    = lane & 15;
    const int quad = lane >> 4;
    const int wm   = (w >> 1) << 6;
    const int wn   = (w & 1) << 6;

    const int srow = lane >> 2;
    const int scol = (lane & 3) << 3;

    floatx4 acc[4][4];
    #pragma unroll
    for (int i = 0; i < 4; i++)
        #pragma unroll
        for (int j = 0; j < 4; j++)
            acc[i][j] = (floatx4){0.f, 0.f, 0.f, 0.f};

    for (int k0 = 0; k0 < K; k0 += 32) {
        __syncthreads();
        #pragma unroll
        for (int p = 0; p < 2; ++p) {
            const int rbase = p*64 + w*16;
            gld_lds16(&A[(size_t)(m0 + rbase + srow)*K + k0 + scol], &As[rbase*32]);
            gld_lds16(&B[(size_t)(n0 + rbase + srow)*K + k0 + scol], &Bs[rbase*32]);
        }
        __syncthreads();

        half8 af[4], bf[4];
        #pragma unroll
        for (int i = 0; i < 4; i++)
            af[i] = *(const half8*)&As[(wm + i*16 + r)*32 + quad*8];
        #pragma unroll
        for (int j = 0; j < 4; j++)
            bf[j] = *(const half8*)&Bs[(wn + j*16 + r)*32 + quad*8];

        #pragma unroll
        for (int i = 0; i < 4; i++)
            #pragma unroll
            for (int j = 0; j < 4; j++)
                acc[i][j] = __builtin_amdgcn_mfma_f32_16x16x32_f16(
                                af[i], bf[j], acc[i][j], 0, 0, 0);
    }

    // C/D layout: col = lane&15, row = quad*4 + reg
    #pragma unroll
    for (int i = 0; i < 4; i++) {
        #pragma unroll
        for (int j = 0; j < 4; j++) {
            #pragma unroll
            for (int v = 0; v < 4; v++) {
                const int m = m0 + wm + i*16 + quad*4 + v;
                const int n = n0 + wn + j*16 + r;
                const float val = acc[i][j][v];
                if (MODE == 0) {
                    ((float*)Cout)[(size_t)m*N + n] = val;
                } else {
                    const int b = m >> 11, s = m & 2047;
                    const int h = n >> 6,  d = n & 63;
                    ((_Float16*)Cout)[((((size_t)b*NUM_HEADS + h)*HEAD_DIM + d) << 11) + s]
                        = (_Float16)val;
                }
            }
        }
    }
}

// ---------------------------------------------------------------------------
// Split-precision GEMM for Q/K projections with fused RoPE epilogue.
// C = (Ah+Al) @ (Bh+Bl)^T  ~=  Ah·Bh + Ah·Bl + Al·Bh   (3 MFMA chains)
// Output: head-split [b][h][s][64], hi/lo f16 planes — plain, no swizzle.
// ---------------------------------------------------------------------------
__global__ __launch_bounds__(256)
void gemm_qk(const _Float16* __restrict__ Ah, const _Float16* __restrict__ Al,
             const _Float16* __restrict__ Bh, const _Float16* __restrict__ Bl,
             _Float16* __restrict__ Chi, _Float16* __restrict__ Clo,
             const float2* __restrict__ tab, int M, int N, int K) {
    __shared__ _Float16 Ash[128*32];
    __shared__ _Float16 Asl[128*32];
    __shared__ _Float16 Bsh[128*32];
    __shared__ _Float16 Bsl[128*32];

    const int nb = N >> 7;
    const int bx = blockIdx.x % nb;
    const int by = blockIdx.x / nb;
    const int m0 = by << 7, n0 = bx << 7;

    const int t    = threadIdx.x;
    const int w    = t >> 6;
    const int lane = t & 63;
    const int r    = lane & 15;
    const int quad = lane >> 4;
    const int wm   = (w >> 1) << 6;
    const int wn   = (w & 1) << 6;

    const int srow = lane >> 2;
    const int scol = (lane & 3) << 3;

    floatx4 acc[4][4];
    #pragma unroll
    for (int i = 0; i < 4; i++)
        #pragma unroll
        for (int j = 0; j < 4; j++)
            acc[i][j] = (floatx4){0.f, 0.f, 0.f, 0.f};

    for (int k0 = 0; k0 < K; k0 += 32) {
        __syncthreads();
        #pragma unroll
        for (int p = 0; p < 2; ++p) {
            const int rbase = p*64 + w*16;
            const size_t ga = (size_t)(m0 + rbase + srow)*K + k0 + scol;
            const size_t gb = (size_t)(n0 + rbase + srow)*K + k0 + scol;
            gld_lds16(&Ah[ga], &Ash[rbase*32]);
            gld_lds16(&Al[ga], &Asl[rbase*32]);
            gld_lds16(&Bh[gb], &Bsh[rbase*32]);
            gld_lds16(&Bl[gb], &Bsl[rbase*32]);
        }
        __syncthreads();

        half8 ah[4], al[4], bh[4], bl[4];
        #pragma unroll
        for (int i = 0; i < 4; i++) {
            ah[i] = *(const half8*)&Ash[(wm + i*16 + r)*32 + quad*8];
            al[i] = *(const half8*)&Asl[(wm + i*16 + r)*32 + quad*8];
        }
        #pragma unroll
        for (int j = 0; j < 4; j++) {
            bh[j] = *(const half8*)&Bsh[(wn + j*16 + r)*32 + quad*8];
            bl[j] = *(const half8*)&Bsl[(wn + j*16 + r)*32 + quad*8];
        }

        #pragma unroll
        for (int i = 0; i < 4; i++)
            #pragma unroll
            for (int j = 0; j < 4; j++) {
                acc[i][j] = __builtin_amdgcn_mfma_f32_16x16x32_f16(
                                ah[i], bh[j], acc[i][j], 0, 0, 0);
                acc[i][j] = __builtin_amdgcn_mfma_f32_16x16x32_f16(
                                ah[i], bl[j], acc[i][j], 0, 0, 0);
                acc[i][j] = __builtin_amdgcn_mfma_f32_16x16x32_f16(
                                al[i], bh[j], acc[i][j], 0, 0, 0);
            }
    }

    // Epilogue: RoPE + split-f16 store. Pair partner is lane^1 (adjacent n).
    #pragma unroll
    for (int i = 0; i < 4; i++) {
        #pragma unroll
        for (int v = 0; v < 4; v++) {
            const int m  = m0 + wm + i*16 + quad*4 + v;
            const int b  = m >> 11;
            const int s_ = m & 2047;
            #pragma unroll
            for (int j = 0; j < 4; j++) {
                const int n = n0 + wn + j*16 + r;
                const int h = n >> 6, d = n & 63;
                const float val = acc[i][j][v];
                const float pv  = __shfl_xor(val, 1);
                const float2 cs = tab[s_*32 + (d >> 1)];
                const float res = (r & 1) ? (pv*cs.y + val*cs.x)
                                          : (val*cs.x - pv*cs.y);
                const size_t idx = ((((size_t)b*NUM_HEADS + h)*SEQ + s_) << 6) + d;
                const _Float16 hv = (_Float16)res;
                Chi[idx] = hv;
                Clo[idx] = (_Float16)(res - (float)hv);
            }
        }
    }
}

// ---------------------------------------------------------------------------
// Causal flash attention, block-cooperative, transposed scores.
// 256 threads = 4 waves; block handles 64 Q-rows (wave w: rows q0+w*16..+15).
// 64-key iterations. K (hi/lo) and V^T tiles staged in LDS as 64x32 HALF-TILES
// (K split by d-halves, V^T split by key-halves): LDS rows are 64 B, so each
// ds_read_b128 fragment read covers 16 contiguous rows = contiguous 1024 B
// -> conflict-free (m97 shape), no swizzle, global layouts untouched.
// S^T = K·Q^T  (q in lane&15 -> softmax reductions are 2 shuffles).
// O^T = V^T·P  (q in lane&15 -> alpha rescale is shuffle-free).
// Longest blocks launch first (LPT) to kill the drain tail.
// ---------------------------------------------------------------------------
#define PSTR 72   // P strip stride in f16
__global__ __launch_bounds__(256)
void flash_attn(const _Float16* __restrict__ Qhi, const _Float16* __restrict__ Qlo,
                const _Float16* __restrict__ Khi, const _Float16* __restrict__ Klo,
                const _Float16* __restrict__ Vt,  _Float16* __restrict__ AO) {
    __shared__ _Float16 Ksh0[64*32];   // K hi, d [0,32)
    __shared__ _Float16 Ksh1[64*32];   // K hi, d [32,64)
    __shared__ _Float16 Ksl0[64*32];   // K lo, d [0,32)
    __shared__ _Float16 Ksl1[64*32];   // K lo, d [32,64)
    __shared__ _Float16 Vs0 [64*32];   // V^T, keys [0,32)
    __shared__ _Float16 Vs1 [64*32];   // V^T, keys [32,64)
    __shared__ _Float16 Pl  [4][16*PSTR];

    const int t    = threadIdx.x;
    const int w    = t >> 6;
    const int lane = t & 63;
    const int r    = lane & 15;
    const int quad = lane >> 4;

    const int bx = blockIdx.x;
    const int bh = bx & 63;                 // 64 bh, fastest
    const int qb = 31 - (bx >> 6);          // 32 q-blocks, longest first
    const int q0w = qb*64 + w*16;
    const int b  = bh >> 4, h = bh & 15;

    const _Float16* Qh_ = Qhi + (size_t)bh * SEQ * HEAD_DIM;
    const _Float16* Ql_ = Qlo + (size_t)bh * SEQ * HEAD_DIM;
    const _Float16* Khg = Khi + (size_t)bh * SEQ * HEAD_DIM;
    const _Float16* Klg = Klo + (size_t)bh * SEQ * HEAD_DIM;
    const _Float16* Vtg = Vt  + (size_t)bh * HEAD_DIM * SEQ;

    // Q B-fragments: B[n=q=r][k=d=c*32+quad*8+j], hi and lo (global, plain)
    half8 qh[2], ql[2];
    #pragma unroll
    for (int c = 0; c < 2; ++c) {
        qh[c] = *(const half8*)&Qh_[(size_t)(q0w + r)*64 + c*32 + quad*8];
        ql[c] = *(const half8*)&Ql_[(size_t)(q0w + r)*64 + c*32 + quad*8];
    }

    // O^T accumulators: tile d = dt*16+quad*4+v, col q = r
    floatx4 ot[4];
    #pragma unroll
    for (int dt = 0; dt < 4; ++dt) ot[dt] = (floatx4){0.f,0.f,0.f,0.f};
    float mi = -1e30f, li = 0.f;

    // staging: 16-row strip per wave; lane -> (row = lane>>2, 16B chunk = lane&3)
    const int sr = lane >> 2;
    const int sc = (lane & 3) << 3;

    const int niter = qb + 1;
    for (int kt = 0; kt < niter; ++kt) {
        const int k0 = kt << 6;

        __syncthreads();                  // prior iter's LDS reads complete
        {
            const int rb  = w << 4;       // wave-uniform strip base (w*16)
            const int row = rb + sr;
            const size_t kr = (size_t)(k0 + row)*64;
            gld_lds16(&Khg[kr +      sc], &Ksh0[rb*32]);
            gld_lds16(&Khg[kr + 32 + sc], &Ksh1[rb*32]);
            gld_lds16(&Klg[kr +      sc], &Ksl0[rb*32]);
            gld_lds16(&Klg[kr + 32 + sc], &Ksl1[rb*32]);
            const size_t vr = (size_t)row*SEQ + k0;
            gld_lds16(&Vtg[vr +      sc], &Vs0[rb*32]);
            gld_lds16(&Vtg[vr + 32 + sc], &Vs1[rb*32]);
        }
        __syncthreads();                  // vmcnt(0): staging complete

        // S^T = K·Q^T : 16 scores per lane (key = sub*16+quad*4+v, q = r)
        float s[16];
        #pragma unroll
        for (int sub = 0; sub < 4; ++sub) {
            floatx4 a = (floatx4){0.f,0.f,0.f,0.f};
            const int fr = (sub*16 + r)*32 + quad*8;   // contiguous 1024B/read
            const half8 kh0 = *(const half8*)&Ksh0[fr];
            const half8 kh1 = *(const half8*)&Ksh1[fr];
            const half8 kl0 = *(const half8*)&Ksl0[fr];
            const half8 kl1 = *(const half8*)&Ksl1[fr];
            a = __builtin_amdgcn_mfma_f32_16x16x32_f16(kh0, qh[0], a, 0, 0, 0);
            a = __builtin_amdgcn_mfma_f32_16x16x32_f16(kh1, qh[1], a, 0, 0, 0);
            a = __builtin_amdgcn_mfma_f32_16x16x32_f16(kh0, ql[0], a, 0, 0, 0);
            a = __builtin_amdgcn_mfma_f32_16x16x32_f16(kh1, ql[1], a, 0, 0, 0);
            a = __builtin_amdgcn_mfma_f32_16x16x32_f16(kl0, qh[0], a, 0, 0, 0);
            a = __builtin_amdgcn_mfma_f32_16x16x32_f16(kl1, qh[1], a, 0, 0, 0);
            #pragma unroll
            for (int v = 0; v < 4; ++v) s[sub*4 + v] = a[v] * 0.125f;
        }

        if (kt == niter - 1) {            // causal mask only in the last tile
            #pragma unroll
            for (int sub = 0; sub < 4; ++sub)
                #pragma unroll
                for (int v = 0; v < 4; ++v)
                    if (k0 + sub*16 + quad*4 + v > q0w + r)
                        s[sub*4 + v] = -1e30f;
        }

        // online softmax over this tile's 64 keys (per lane: q = r)
        float tm = s[0];
        #pragma unroll
        for (int i = 1; i < 16; ++i) tm = fmaxf(tm, s[i]);
        tm = fmaxf(tm, __shfl_xor(tm, 16));
        tm = fmaxf(tm, __shfl_xor(tm, 32));
        const float mn = fmaxf(mi, tm);
        const float alpha = __expf(mi - mn);
        mi = mn;
        float rs = 0.f;
        #pragma unroll
        for (int i = 0; i < 16; ++i) { s[i] = __expf(s[i] - mn); rs += s[i]; }
        rs += __shfl_xor(rs, 16);
        rs += __shfl_xor(rs, 32);
        li = li*alpha + rs;
        #pragma unroll
        for (int dt = 0; dt < 4; ++dt)
            #pragma unroll
            for (int v = 0; v < 4; ++v) ot[dt][v] *= alpha;

        // P^T -> per-wave LDS strip [q=r][key], packed 4-wide
        #pragma unroll
        for (int sub = 0; sub < 4; ++sub) {
            half4v pk = { (_Float16)s[sub*4+0], (_Float16)s[sub*4+1],
                          (_Float16)s[sub*4+2], (_Float16)s[sub*4+3] };
            *(half4v*)&Pl[w][r*PSTR + sub*16 + quad*4] = pk;
        }
        // (same-wave write->read: compiler inserts lgkmcnt wait, no barrier)

        // O^T += V^T·P : A = V^T-frag [m=d][k=key], B = P [n=q][k=key]
        #pragma unroll
        for (int c = 0; c < 2; ++c) {
            const half8 pf = *(const half8*)&Pl[w][r*PSTR + c*32 + quad*8];
            const _Float16* Vsc = c ? Vs1 : Vs0;
            #pragma unroll
            for (int dt = 0; dt < 4; ++dt) {
                const half8 vf = *(const half8*)&Vsc[(dt*16 + r)*32 + quad*8];
                ot[dt] = __builtin_amdgcn_mfma_f32_16x16x32_f16(vf, pf, ot[dt], 0, 0, 0);
            }
        }
    }

    // epilogue: normalize, write AO [b][s=q][h*64 + d] (8B stores)
    const float inv = 1.0f / li;
    const int q = q0w + r;
    #pragma unroll
    for (int dt = 0; dt < 4; ++dt) {
        half4v o = { (_Float16)(ot[dt][0]*inv), (_Float16)(ot[dt][1]*inv),
                     (_Float16)(ot[dt][2]*inv), (_Float16)(ot[dt][3]*inv) };
        *(half4v*)&AO[((size_t)(b*SEQ + q))*D_MODEL + h*HEAD_DIM + dt*16 + quad*4] = o;
    }
}

// ---------------------------------------------------------------------------
extern "C" void kernel_launch(void* const* d_in, const int* in_sizes, int n_in,
                              void* d_out, int out_size, void* d_ws, size_t ws_size,
                              hipStream_t stream) {
    const float* x  = (const float*)d_in[0];
    const float* qw = (const float*)d_in[1];
    const float* kw = (const float*)d_in[2];
    const float* vw = (const float*)d_in[3];
    const float* ow = (const float*)d_in[4];
    float* out = (float*)d_out;

    // workspace layout (_Float16 counts), total ~147.3 MB
    _Float16* xh  = (_Float16*)d_ws;
    _Float16* xl  = xh  + (size_t)MROWS * D_MODEL;
    _Float16* qwh = xl  + (size_t)MROWS * D_MODEL;
    _Float16* qwl = qwh + (size_t)D_MODEL * D_MODEL;
    _Float16* kwh = qwl + (size_t)D_MODEL * D_MODEL;
    _Float16* kwl = kwh + (size_t)D_MODEL * D_MODEL;
    _Float16* vwh = kwl + (size_t)D_MODEL * D_MODEL;
    _Float16* owh = vwh + (size_t)D_MODEL * D_MODEL;
    _Float16* Qhi = owh + (size_t)D_MODEL * D_MODEL;
    _Float16* Qlo = Qhi + (size_t)MROWS * D_MODEL;
    _Float16* Khi = Qlo + (size_t)MROWS * D_MODEL;
    _Float16* Klo = Khi + (size_t)MROWS * D_MODEL;
    _Float16* Vt  = Klo + (size_t)MROWS * D_MODEL;
    _Float16* AO  = Vt  + (size_t)MROWS * D_MODEL;
    float2*   tab = (float2*)(AO + (size_t)MROWS * D_MODEL);

    rope_table<<<(SEQ*32)/256, 256, 0, stream>>>(tab);

    const int nx4 = MROWS * D_MODEL / 4;
    f32_split_f16<<<nx4/256, 256, 0, stream>>>(x, xh, xl, nx4);
    const int nw4 = D_MODEL * D_MODEL / 4;
    f32_split_f16<<<nw4/256, 256, 0, stream>>>(qw, qwh, qwl, nw4);
    f32_split_f16<<<nw4/256, 256, 0, stream>>>(kw, kwh, kwl, nw4);
    f32_to_f16_v4<<<nw4/256, 256, 0, stream>>>(vw, vwh, nw4);
    f32_to_f16_v4<<<nw4/256, 256, 0, stream>>>(ow, owh, nw4);

    const int gemm_grid = (MROWS/128) * (D_MODEL/128);   // 512
    gemm_qk<<<gemm_grid, 256, 0, stream>>>(xh, xl, qwh, qwl, Qhi, Qlo, tab,
                                           MROWS, D_MODEL, D_MODEL);
    gemm_qk<<<gemm_grid, 256, 0, stream>>>(xh, xl, kwh, kwl, Khi, Klo, tab,
                                           MROWS, D_MODEL, D_MODEL);
    gemm_bt<2><<<gemm_grid, 256, 0, stream>>>(xh, vwh, Vt, MROWS, D_MODEL, D_MODEL);

    flash_attn<<<BH * (SEQ/64), 256, 0, stream>>>(Qhi, Qlo, Khi, Klo, Vt, AO);

    gemm_bt<0><<<gemm_grid, 256, 0, stream>>>(AO, owh, out, MROWS, D_MODEL, D_MODEL);
}